// Round 3
// baseline (120.709 us; speedup 1.0000x reference)
//
#include <hip/hip_runtime.h>
#include <math.h>

#define BATCH 131072
#define EPS 1e-8f
#define OVF_CAP 16384u

// ws layout (floats):
// [0..255]    logw (16x16, [j][0]=0)
// [256..511]  M = L0^{-1} (row-major M[i][j] at 256+i*16+j)
// [512]       logdet(L0)
// [513]       alpha = logdet(L0+I)
// [514]       overflow count (uint)
// [520..]     overflow list: (b, Zmask) int pairs, cap OVF_CAP

// Column-masked 16x16 LU logdet: columns with mask bit OFF are e_j; pad
// pivots stay 1 through elimination (verified R2), active pivots equal those
// of LU(Mat[S,S]) -> returns logdet(Mat[S,S]). No pivoting needed: Mat's
// symmetric part is PD, so all principal minors > 0.
__device__ __forceinline__ float lu_logdet_mask(const float* sMat, unsigned m) {
    float a[16][16];
    #pragma unroll
    for (int j = 0; j < 16; ++j) {
        bool on = (m >> j) & 1u;
        #pragma unroll
        for (int i = 0; i < 16; ++i) {
            float v = on ? sMat[i * 16 + j] : 0.f;
            if (i == j && !on) v = 1.f;
            a[i][j] = v;
        }
    }
    float logdet = 0.f;
    #pragma unroll
    for (int k = 0; k < 16; ++k) {
        float piv = a[k][k];
        logdet += __logf(fabsf(piv));
        float inv = 1.0f / piv;
        #pragma unroll
        for (int i2 = k + 1; i2 < 16; ++i2) {
            float f = a[i2][k] * inv;
            #pragma unroll
            for (int j2 = k + 1; j2 < 16; ++j2)
                a[i2][j2] = fmaf(-f, a[k][j2], a[i2][j2]);
        }
    }
    return logdet;
}

// 1 block x 256 threads (4 waves). Wave 0: LU(L0) + 16 column solves -> M,
// logdet(L0). Wave 1: logdet(L0+I) -> alpha. Wave 2: log-softmax rows.
// Wave 3: zero overflow counter. Wave-uniform branches only.
__global__ __launch_bounds__(256) void prep_kernel(
    const float* __restrict__ W, const float* __restrict__ A,
    const float* __restrict__ Bm, const float* __restrict__ Cm,
    float* __restrict__ ws) {
    __shared__ float sL0[256];
    int t = threadIdx.x;
    {
        int i = t >> 4, j = t & 15;
        float s = 0.f;
        #pragma unroll
        for (int k = 0; k < 16; ++k) {
            s += A[k * 16 + i] * A[k * 16 + j];
            s += Bm[i * 16 + k] * Cm[j * 16 + k]
               - Cm[i * 16 + k] * Bm[j * 16 + k];
        }
        if (i == j) s += EPS;
        sL0[t] = s;
    }
    __syncthreads();

    int w = t >> 6, lt = t & 63;
    if (w == 0) {
        // Per-lane LU of L0 with stored multipliers (all lanes identical work).
        float a[16][16];
        #pragma unroll
        for (int i = 0; i < 16; ++i)
            #pragma unroll
            for (int j = 0; j < 16; ++j) a[i][j] = sL0[i * 16 + j];
        float logdet = 0.f;
        #pragma unroll
        for (int k = 0; k < 16; ++k) {
            float piv = a[k][k];
            logdet += __logf(fabsf(piv));
            float inv = 1.0f / piv;
            #pragma unroll
            for (int i2 = k + 1; i2 < 16; ++i2) {
                float f = a[i2][k] * inv;
                a[i2][k] = f;  // store L
                #pragma unroll
                for (int j2 = k + 1; j2 < 16; ++j2)
                    a[i2][j2] = fmaf(-f, a[k][j2], a[i2][j2]);
            }
        }
        // Lane c solves L0 x = e_c -> column c of M (lanes 16-63 redundant).
        int c = lt & 15;
        float y[16];
        #pragma unroll
        for (int i = 0; i < 16; ++i) {
            float v = (i == c) ? 1.f : 0.f;
            #pragma unroll
            for (int k = 0; k < 16; ++k)
                if (k < i) v = fmaf(-a[i][k], y[k], v);
            y[i] = v;
        }
        float xc[16];
        #pragma unroll
        for (int i = 15; i >= 0; --i) {
            float v = y[i];
            #pragma unroll
            for (int k = 0; k < 16; ++k)
                if (k > i) v = fmaf(-a[i][k], xc[k], v);
            xc[i] = v / a[i][i];
        }
        if (lt < 16) {
            #pragma unroll
            for (int i = 0; i < 16; ++i) ws[256 + i * 16 + c] = xc[i];
        }
        if (lt == 0) ws[512] = logdet;
    } else if (w == 1) {
        if (lt == 0) ws[513] = lu_logdet_mask(sL0, 0xFFFFu) == 0.f ? 0.f : 0.f;
        // (dummy line removed below — real alpha computed by all lanes)
        float a[16][16];
        #pragma unroll
        for (int i = 0; i < 16; ++i)
            #pragma unroll
            for (int j = 0; j < 16; ++j)
                a[i][j] = sL0[i * 16 + j] + ((i == j) ? 1.f : 0.f);
        float logdet = 0.f;
        #pragma unroll
        for (int k = 0; k < 16; ++k) {
            float piv = a[k][k];
            logdet += __logf(fabsf(piv));
            float inv = 1.0f / piv;
            #pragma unroll
            for (int i2 = k + 1; i2 < 16; ++i2) {
                float f = a[i2][k] * inv;
                #pragma unroll
                for (int j2 = k + 1; j2 < 16; ++j2)
                    a[i2][j2] = fmaf(-f, a[k][j2], a[i2][j2]);
            }
        }
        if (lt == 0) ws[513] = logdet;
    } else if (w == 2) {
        int r = lt & 15;
        float row[15];
        float mx = -1e30f;
        #pragma unroll
        for (int q = 0; q < 15; ++q) {
            row[q] = W[r * 15 + q];
            mx = fmaxf(mx, row[q]);
        }
        float se = 0.f;
        #pragma unroll
        for (int q = 0; q < 15; ++q) se += expf(row[q] - mx);
        float lse = mx + logf(se);
        if (lt < 16) {
            ws[r * 16 + 0] = 0.f;
            #pragma unroll
            for (int q = 0; q < 15; ++q) ws[r * 16 + 1 + q] = row[q] - lse;
        }
    } else {
        if (lt == 0) ((unsigned*)ws)[514] = 0u;
    }
}

__global__ __launch_bounds__(256) void main_kernel(const int4* __restrict__ x,
                                                   float* __restrict__ ws,
                                                   float* __restrict__ out) {
    __shared__ float s[512];  // [0..255] logw, [256..511] M
    int lt = threadIdx.x;
    s[lt] = ws[lt];
    s[256 + lt] = ws[256 + lt];
    __syncthreads();

    int b = blockIdx.x * 256 + lt;
    const int4* xb = x + (size_t)b * 16;

    float lw = 0.f;
    unsigned mask = 0;
    #pragma unroll
    for (int j = 0; j < 16; ++j) {
        int4 v = xb[j];
        int idx = v.x + 2 * v.y + 4 * v.z + 8 * v.w;
        lw += s[j * 16 + idx];
        mask |= (idx != 0 ? 1u : 0u) << j;
    }
    unsigned zb = (~mask) & 0xFFFFu;
    int z = __popc(zb);
    float base = lw + ws[512] - ws[513];

    if (z <= 4) {
        int zi[4];
        unsigned tt = zb;
        #pragma unroll
        for (int q = 0; q < 4; ++q) {
            zi[q] = tt ? (__ffs(tt) - 1) : 15;
            tt &= tt - 1;
        }
        float m[4][4];
        #pragma unroll
        for (int r = 0; r < 4; ++r)
            #pragma unroll
            for (int c = 0; c < 4; ++c) {
                float v = s[256 + zi[r] * 16 + zi[c]];
                m[r][c] = (r < z && c < z) ? v : ((r == c) ? 1.f : 0.f);
            }
        float s0 = m[2][2] * m[3][3] - m[2][3] * m[3][2];
        float s1 = m[2][1] * m[3][3] - m[2][3] * m[3][1];
        float s2 = m[2][1] * m[3][2] - m[2][2] * m[3][1];
        float s3 = m[2][0] * m[3][3] - m[2][3] * m[3][0];
        float s4 = m[2][0] * m[3][2] - m[2][2] * m[3][0];
        float s5 = m[2][0] * m[3][1] - m[2][1] * m[3][0];
        float c0 = m[1][1] * s0 - m[1][2] * s1 + m[1][3] * s2;
        float c1 = m[1][0] * s0 - m[1][2] * s3 + m[1][3] * s4;
        float c2 = m[1][0] * s1 - m[1][1] * s3 + m[1][3] * s5;
        float c3 = m[1][0] * s2 - m[1][1] * s4 + m[1][2] * s5;
        float det = m[0][0] * c0 - m[0][1] * c1 + m[0][2] * c2 - m[0][3] * c3;
        out[b] = base + __logf(fabsf(det));
    } else {
        unsigned pos = atomicAdd(((unsigned*)ws) + 514, 1u);
        if (pos < OVF_CAP) {
            ((int*)ws)[520 + 2 * pos] = b;
            ((int*)ws)[521 + 2 * pos] = (int)zb;
        }
        out[b] = base;  // correction added by cleanup_kernel
    }
}

// 1 block x 64 threads: full 16x16 column-masked LU on M for rare z>=5.
__global__ __launch_bounds__(64) void cleanup_kernel(const float* __restrict__ ws,
                                                     float* __restrict__ out) {
    __shared__ float sM[256];
    int lt = threadIdx.x;
    #pragma unroll
    for (int q = 0; q < 4; ++q) sM[lt * 4 + q] = ws[256 + lt * 4 + q];
    __syncthreads();

    unsigned n = ((const unsigned*)ws)[514];
    if (n > OVF_CAP) n = OVF_CAP;
    for (unsigned ii = (unsigned)lt; ii < n; ii += 64u) {
        int b = ((const int*)ws)[520 + 2 * ii];
        unsigned Z = (unsigned)((const int*)ws)[521 + 2 * ii];
        out[b] += lu_logdet_mask(sM, Z);
    }
}

extern "C" void kernel_launch(void* const* d_in, const int* in_sizes, int n_in,
                              void* d_out, int out_size, void* d_ws, size_t ws_size,
                              hipStream_t stream) {
    const int4*  x = (const int4*)d_in[0];
    const float* W = (const float*)d_in[1];
    const float* A = (const float*)d_in[2];
    const float* B = (const float*)d_in[3];
    const float* C = (const float*)d_in[4];
    float* ws  = (float*)d_ws;
    float* out = (float*)d_out;

    prep_kernel<<<1, 256, 0, stream>>>(W, A, B, C, ws);
    main_kernel<<<BATCH / 256, 256, 0, stream>>>(x, ws, out);
    cleanup_kernel<<<1, 64, 0, stream>>>(ws, out);
}

// Round 5
// 105.675 us; speedup vs baseline: 1.1423x; 1.1423x over previous
//
#include <hip/hip_runtime.h>
#include <math.h>

#define BATCH 131072
#define EPS 1e-8f
#define OVF_CAP 16384u

// ws layout (floats):
// [0..271]    logw padded stride 17: logw[j*17+idx], idx 0 -> 0.0
// [272..527]  M = L0^{-1} packed row-major (16x16)
// [528]       logdet(L0)
// [529]       alpha = logdet(L0+I)
// [530]       overflow count (uint)
// [544..]     overflow list: (b, Zmask) int pairs, cap OVF_CAP

// ---------------------------------------------------------------------------
// prep: 1 block x 256 threads. Cooperative in-LDS Gauss-Jordan: M = L0^-1 and
// logdet(L0) (pivot products; unpivoted is valid: sym part of L0 = A^T A+eps*I
// is PD so all leading minors > 0). Simultaneous in-LDS LU of L0+I -> alpha.
// No per-thread matrix arrays -> no spills, short serial latency.
// ---------------------------------------------------------------------------
__global__ __launch_bounds__(256) void prep_kernel(
    const float* __restrict__ W, const float* __restrict__ A,
    const float* __restrict__ Bm, const float* __restrict__ Cm,
    float* __restrict__ ws) {
    __shared__ float sAug[16 * 34];   // [i][0..15]=L0, [i][16..31]=I
    __shared__ float sLI[16 * 17];    // L0 + I (LU'd in place)
    int t = threadIdx.x;
    int i = t >> 4, j = t & 15;

    // Build L0 entry (i,j)
    float s = 0.f;
    #pragma unroll
    for (int k = 0; k < 16; ++k) {
        s += A[k * 16 + i] * A[k * 16 + j];    // (A^T A)[i][j]
        s += Bm[i * 16 + k] * Cm[j * 16 + k]   // (B C^T)[i][j]
           - Cm[i * 16 + k] * Bm[j * 16 + k];  // (C B^T)[i][j]
    }
    if (i == j) s += EPS;
    sAug[i * 34 + j] = s;
    sAug[i * 34 + 16 + j] = (i == j) ? 1.f : 0.f;
    sLI[i * 17 + j] = s + ((i == j) ? 1.f : 0.f);
    __syncthreads();

    float logdetAcc = 0.f, alphaAcc = 0.f;
    for (int k = 0; k < 16; ++k) {
        // read phase (pivots pre-normalization: their product == det)
        float piv  = sAug[k * 34 + k];
        float f    = sAug[i * 34 + k];          // GJ factor for row i
        float pivL = sLI[k * 17 + k];
        float g    = sLI[i * 17 + k];           // LU factor for row i
        logdetAcc += __logf(fabsf(piv));
        alphaAcc  += __logf(fabsf(pivL));
        __syncthreads();
        // normalize GJ pivot row (both halves: entries 0..31)
        if (t < 32) sAug[k * 34 + t] *= 1.f / piv;
        __syncthreads();
        // eliminate
        if (i != k) {
            sAug[i * 34 + j]      = fmaf(-f, sAug[k * 34 + j],      sAug[i * 34 + j]);
            sAug[i * 34 + 16 + j] = fmaf(-f, sAug[k * 34 + 16 + j], sAug[i * 34 + 16 + j]);
        }
        if (i > k) {
            sLI[i * 17 + j] = fmaf(-g / pivL, sLI[k * 17 + j], sLI[i * 17 + j]);
        }
        __syncthreads();
    }

    // M packed
    ws[272 + i * 16 + j] = sAug[i * 34 + 16 + j];
    if (t == 0) { ws[528] = logdetAcc; ws[529] = alphaAcc; }
    if (t == 17) ((unsigned*)ws)[530] = 0u;
    if (t == 18) ws[271] = 0.f;   // unused pad slot, keep defined

    // log-softmax rows of W (16x15) -> padded logw table
    if (t < 16) {
        float row[15];
        float mx = -1e30f;
        #pragma unroll
        for (int q = 0; q < 15; ++q) { row[q] = W[t * 15 + q]; mx = fmaxf(mx, row[q]); }
        float se = 0.f;
        #pragma unroll
        for (int q = 0; q < 15; ++q) se += expf(row[q] - mx);
        float lse = mx + logf(se);
        ws[t * 17 + 0] = 0.f;
        #pragma unroll
        for (int q = 0; q < 15; ++q) ws[t * 17 + 1 + q] = row[q] - lse;
    }
}

// ---------------------------------------------------------------------------
// main: 16 lanes per batch element. Thread t of a block reads x4[blk*256+t]
// -> fully coalesced (4 KB contiguous per block). Group-of-16 reduce via
// shfl_xor; zero-part mask via one ballot. z<=5 handled inline with a 5x5
// identity-padded unpivoted LU on M[Z,Z] (Jacobi: det L0[S,S] = det L0 *
// det M[Z,Z]); z>=6 (expected ~1 of 131072) -> overflow list.
// ---------------------------------------------------------------------------
__global__ __launch_bounds__(256) void main_kernel(const int4* __restrict__ x4,
                                                   float* __restrict__ ws,
                                                   float* __restrict__ out) {
    __shared__ float sLW[272];   // logw padded 17
    __shared__ float sM[272];    // M padded 17
    int t = threadIdx.x;
    sLW[t] = ws[t];                                           // 0..255
    if (t < 16) sLW[256 + t] = ws[256 + t];                   // 256..271 (R4 bug fix)
    sM[(t >> 4) * 17 + (t & 15)] = ws[272 + t];               // repack padded
    __syncthreads();

    int l = t & 15;                 // part index
    int grp = t >> 4;               // element within block
    int b = blockIdx.x * 16 + grp;

    int4 v = x4[(size_t)blockIdx.x * 256 + t];   // coalesced
    int idx = v.x + 2 * v.y + 4 * v.z + 8 * v.w; // 0..15
    float lw = sLW[l * 17 + idx];

    unsigned lane = t & 63;
    unsigned long long wmask = __ballot(idx != 0);
    unsigned gm = (unsigned)((wmask >> (lane & 48)) & 0xFFFFull);

    // group sum (xor masks < 16 stay within the 16-lane group)
    lw += __shfl_xor(lw, 1);
    lw += __shfl_xor(lw, 2);
    lw += __shfl_xor(lw, 4);
    lw += __shfl_xor(lw, 8);

    if (l == 0) {
        unsigned zb = (~gm) & 0xFFFFu;
        int z = __popc(zb);
        float base = lw + ws[528] - ws[529];
        if (z <= 5) {
            int zi[5];
            unsigned tt = zb;
            #pragma unroll
            for (int q = 0; q < 5; ++q) {
                zi[q] = tt ? (__ffs(tt) - 1) : 0;
                tt &= tt - 1;
            }
            float m[5][5];
            #pragma unroll
            for (int r = 0; r < 5; ++r)
                #pragma unroll
                for (int c = 0; c < 5; ++c)
                    m[r][c] = (r < z && c < z) ? sM[zi[r] * 17 + zi[c]]
                                               : ((r == c) ? 1.f : 0.f);
            float logd = 0.f;
            #pragma unroll
            for (int k = 0; k < 5; ++k) {
                float piv = m[k][k];
                logd += __logf(fabsf(piv));
                float inv = 1.0f / piv;
                #pragma unroll
                for (int r = k + 1; r < 5; ++r) {
                    float f = m[r][k] * inv;
                    #pragma unroll
                    for (int c = k + 1; c < 5; ++c)
                        m[r][c] = fmaf(-f, m[k][c], m[r][c]);
                }
            }
            out[b] = base + logd;
        } else {
            unsigned pos = atomicAdd(((unsigned*)ws) + 530, 1u);
            if (pos < OVF_CAP) {
                ((int*)ws)[544 + 2 * pos] = b;
                ((int*)ws)[545 + 2 * pos] = (int)zb;
            }
            out[b] = base;   // correction added by cleanup
        }
    }
}

// ---------------------------------------------------------------------------
// cleanup: rare z>=6 items. Column-masked 16x16 unpivoted LU on M (valid for
// any principal submatrix: sym part of M is PD). 8 blocks x 64 lanes,
// one LU per lane. 1 wave/SIMD -> 512-VGPR budget fits the 256-reg array.
// ---------------------------------------------------------------------------
__global__ __launch_bounds__(64, 1) void cleanup_kernel(const float* __restrict__ ws,
                                                        float* __restrict__ out) {
    __shared__ float sM[256];
    int lt = threadIdx.x;
    #pragma unroll
    for (int q = 0; q < 4; ++q) sM[lt * 4 + q] = ws[272 + lt * 4 + q];
    __syncthreads();

    unsigned n = ((const unsigned*)ws)[530];
    if (n > OVF_CAP) n = OVF_CAP;
    unsigned stride = 8u * 64u;
    for (unsigned ii = blockIdx.x * 64u + (unsigned)lt; ii < n; ii += stride) {
        int b = ((const int*)ws)[544 + 2 * ii];
        unsigned Z = (unsigned)((const int*)ws)[545 + 2 * ii];

        float a[16][16];
        #pragma unroll
        for (int j = 0; j < 16; ++j) {
            bool on = (Z >> j) & 1u;
            #pragma unroll
            for (int i = 0; i < 16; ++i) {
                float v2 = on ? sM[i * 16 + j] : 0.f;
                if (i == j && !on) v2 = 1.f;
                a[i][j] = v2;
            }
        }
        float logdet = 0.f;
        #pragma unroll
        for (int k = 0; k < 16; ++k) {
            float piv = a[k][k];
            logdet += __logf(fabsf(piv));
            float inv = 1.0f / piv;
            #pragma unroll
            for (int i2 = k + 1; i2 < 16; ++i2) {
                float f = a[i2][k] * inv;
                #pragma unroll
                for (int j2 = k + 1; j2 < 16; ++j2)
                    a[i2][j2] = fmaf(-f, a[k][j2], a[i2][j2]);
            }
        }
        out[b] += logdet;
    }
}

extern "C" void kernel_launch(void* const* d_in, const int* in_sizes, int n_in,
                              void* d_out, int out_size, void* d_ws, size_t ws_size,
                              hipStream_t stream) {
    const int4*  x = (const int4*)d_in[0];
    const float* W = (const float*)d_in[1];
    const float* A = (const float*)d_in[2];
    const float* B = (const float*)d_in[3];
    const float* C = (const float*)d_in[4];
    float* ws  = (float*)d_ws;
    float* out = (float*)d_out;

    prep_kernel<<<1, 256, 0, stream>>>(W, A, B, C, ws);
    main_kernel<<<BATCH / 16, 256, 0, stream>>>(x, ws, out);
    cleanup_kernel<<<8, 64, 0, stream>>>(ws, out);
}

// Round 6
// 100.882 us; speedup vs baseline: 1.1965x; 1.0475x over previous
//
#include <hip/hip_runtime.h>
#include <math.h>

#define BATCH 131072
#define EPS 1e-8f
#define OVF_CAP 16384u

// ws layout (floats):
// [0..271]    logw padded stride 17: logw[j*17+idx], idx 0 -> 0.0
// [272..527]  M = L0^{-1} packed row-major (16x16)
// [528]       logdet(L0)
// [529]       alpha = logdet(L0+I)
// [530]       overflow count (uint)
// [544..]     overflow list: (b, Zmask) int pairs, cap OVF_CAP

// ---------------------------------------------------------------------------
// prep: ONE wave (64 lanes), launch_bounds(64,1) -> 512-VGPR budget, the
// 256-reg LU array fits. All lanes run a single shared LU instruction
// stream: lanes 16..31 add +1 to the diagonal (L0+I), others factor L0 —
// same instructions, no divergence. Unpivoted LU is valid: sym part of L0
// is A^T A + eps I (PD), so all leading minors > 0; same for L0+I.
// Lane 0 -> logdet(L0); lane 16 -> alpha; lanes 0..15 -> column solves of
// M = L0^{-1}; lanes 32..47 -> log-softmax rows of W.
// ---------------------------------------------------------------------------
__global__ __launch_bounds__(64, 1) void prep_kernel(
    const float* __restrict__ W, const float* __restrict__ A,
    const float* __restrict__ Bm, const float* __restrict__ Cm,
    float* __restrict__ ws) {
    __shared__ float sL0[256];
    int t = threadIdx.x;

    #pragma unroll
    for (int q = 0; q < 4; ++q) {
        int e = t * 4 + q, i = e >> 4, j = e & 15;
        float s = 0.f;
        #pragma unroll
        for (int k = 0; k < 16; ++k) {
            s += A[k * 16 + i] * A[k * 16 + j];    // (A^T A)[i][j]
            s += Bm[i * 16 + k] * Cm[j * 16 + k]   // (B C^T)[i][j]
               - Cm[i * 16 + k] * Bm[j * 16 + k];  // (C B^T)[i][j]
        }
        if (i == j) s += EPS;
        sL0[e] = s;
    }
    __syncthreads();

    float dAdd = (t >= 16 && t < 32) ? 1.f : 0.f;
    float a[16][16];
    #pragma unroll
    for (int i = 0; i < 16; ++i)
        #pragma unroll
        for (int j = 0; j < 16; ++j)
            a[i][j] = sL0[i * 16 + j] + ((i == j) ? dAdd : 0.f);

    float logdet = 0.f;
    #pragma unroll
    for (int k = 0; k < 16; ++k) {
        float piv = a[k][k];
        logdet += __logf(fabsf(piv));
        float inv = 1.0f / piv;
        #pragma unroll
        for (int i2 = k + 1; i2 < 16; ++i2) {
            float f = a[i2][k] * inv;
            a[i2][k] = f;                      // store L multiplier
            #pragma unroll
            for (int j2 = k + 1; j2 < 16; ++j2)
                a[i2][j2] = fmaf(-f, a[k][j2], a[i2][j2]);
        }
    }
    if (t == 0)  ws[528] = logdet;   // logdet(L0)
    if (t == 16) ws[529] = logdet;   // alpha = logdet(L0+I)

    if (t < 16) {                    // lane c: solve L0 x = e_c -> M column c
        int c = t;
        float y[16];
        #pragma unroll
        for (int i = 0; i < 16; ++i) {
            float v = (i == c) ? 1.f : 0.f;
            #pragma unroll
            for (int k = 0; k < 16; ++k)
                if (k < i) v = fmaf(-a[i][k], y[k], v);
            y[i] = v;
        }
        float xc[16];
        #pragma unroll
        for (int i = 15; i >= 0; --i) {
            float v = y[i];
            #pragma unroll
            for (int k = 0; k < 16; ++k)
                if (k > i) v = fmaf(-a[i][k], xc[k], v);
            xc[i] = v / a[i][i];
        }
        #pragma unroll
        for (int i = 0; i < 16; ++i) ws[272 + i * 16 + c] = xc[i];
    }

    if (t >= 32 && t < 48) {         // log-softmax row r of W (16x15)
        int r = t - 32;
        float row[15];
        float mx = -1e30f;
        #pragma unroll
        for (int q = 0; q < 15; ++q) { row[q] = W[r * 15 + q]; mx = fmaxf(mx, row[q]); }
        float se = 0.f;
        #pragma unroll
        for (int q = 0; q < 15; ++q) se += expf(row[q] - mx);
        float lse = mx + logf(se);
        ws[r * 17 + 0] = 0.f;
        #pragma unroll
        for (int q = 0; q < 15; ++q) ws[r * 17 + 1 + q] = row[q] - lse;
    }
    if (t == 48) ((unsigned*)ws)[530] = 0u;
    if (t == 49) ws[271] = 0.f;      // pad slot, keep defined
}

// ---------------------------------------------------------------------------
// main: block = 1024 threads = 64 elements x 16 parts. Thread t reads
// x4[blk*1024+t] -> fully coalesced 16 KB/block. Per-group shfl-reduce of
// log-weights + ballot for the zero-part mask; leaders park (lw, gm) in LDS;
// then WAVE 0 ALONE does the 64 determinant corrections at full 64/64 lane
// utilization (waves 1-15 skip via execz). z<=5 inline 5x5 identity-padded
// unpivoted LU on M[Z,Z] (Jacobi: det L0[S,S] = det L0 * det M[Z,Z]);
// z>=6 (expected ~30 of 131072) -> overflow list for cleanup.
// ---------------------------------------------------------------------------
__global__ __launch_bounds__(1024) void main_kernel(const int4* __restrict__ x4,
                                                    float* __restrict__ ws,
                                                    float* __restrict__ out) {
    __shared__ float sLW[272];     // logw padded 17
    __shared__ float sM[272];      // M padded 17
    __shared__ float sLw[64];
    __shared__ unsigned sGm[64];
    int t = threadIdx.x;
    if (t < 272) sLW[t] = ws[t];
    else if (t >= 288 && t < 544) {
        int u = t - 288;
        sM[(u >> 4) * 17 + (u & 15)] = ws[272 + u];
    }
    __syncthreads();

    int l = t & 15;                // part index
    int g = t >> 4;                // element within block (0..63)

    int4 v = x4[(size_t)blockIdx.x * 1024 + t];    // coalesced
    int idx = v.x + 2 * v.y + 4 * v.z + 8 * v.w;   // 0..15
    float lw = sLW[l * 17 + idx];

    unsigned lane = t & 63;
    unsigned long long wmask = __ballot(idx != 0);
    unsigned gm = (unsigned)((wmask >> (lane & 48)) & 0xFFFFull);

    lw += __shfl_xor(lw, 1);
    lw += __shfl_xor(lw, 2);
    lw += __shfl_xor(lw, 4);
    lw += __shfl_xor(lw, 8);

    if (l == 0) { sLw[g] = lw; sGm[g] = gm; }
    __syncthreads();

    if (t < 64) {                  // wave 0: one element per lane
        int b = blockIdx.x * 64 + t;
        unsigned zb = (~sGm[t]) & 0xFFFFu;
        int z = __popc(zb);
        float base = sLw[t] + ws[528] - ws[529];
        if (z <= 5) {
            int zi[5];
            unsigned tt = zb;
            #pragma unroll
            for (int q = 0; q < 5; ++q) {
                zi[q] = tt ? (__ffs(tt) - 1) : 0;
                tt &= tt - 1;
            }
            float m[5][5];
            #pragma unroll
            for (int r = 0; r < 5; ++r)
                #pragma unroll
                for (int c = 0; c < 5; ++c)
                    m[r][c] = (r < z && c < z) ? sM[zi[r] * 17 + zi[c]]
                                               : ((r == c) ? 1.f : 0.f);
            float logd = 0.f;
            #pragma unroll
            for (int k = 0; k < 5; ++k) {
                float piv = m[k][k];
                logd += __logf(fabsf(piv));
                float inv = 1.0f / piv;
                #pragma unroll
                for (int r = k + 1; r < 5; ++r) {
                    float f = m[r][k] * inv;
                    #pragma unroll
                    for (int c = k + 1; c < 5; ++c)
                        m[r][c] = fmaf(-f, m[k][c], m[r][c]);
                }
            }
            out[b] = base + logd;
        } else {
            unsigned pos = atomicAdd(((unsigned*)ws) + 530, 1u);
            if (pos < OVF_CAP) {
                ((int*)ws)[544 + 2 * pos] = b;
                ((int*)ws)[545 + 2 * pos] = (int)zb;
            }
            out[b] = base;         // correction added by cleanup
        }
    }
}

// ---------------------------------------------------------------------------
// cleanup: rare z>=6 items. Column-masked 16x16 unpivoted LU on M (valid for
// any principal submatrix: sym part of M is PD). 8 blocks x 64 lanes, one LU
// per lane; launch_bounds(64,1) -> 256-reg array fits without spilling.
// ---------------------------------------------------------------------------
__global__ __launch_bounds__(64, 1) void cleanup_kernel(const float* __restrict__ ws,
                                                        float* __restrict__ out) {
    __shared__ float sM[256];
    int lt = threadIdx.x;
    #pragma unroll
    for (int q = 0; q < 4; ++q) sM[lt * 4 + q] = ws[272 + lt * 4 + q];
    __syncthreads();

    unsigned n = ((const unsigned*)ws)[530];
    if (n > OVF_CAP) n = OVF_CAP;
    unsigned stride = 8u * 64u;
    for (unsigned ii = blockIdx.x * 64u + (unsigned)lt; ii < n; ii += stride) {
        int b = ((const int*)ws)[544 + 2 * ii];
        unsigned Z = (unsigned)((const int*)ws)[545 + 2 * ii];

        float a[16][16];
        #pragma unroll
        for (int j = 0; j < 16; ++j) {
            bool on = (Z >> j) & 1u;
            #pragma unroll
            for (int i = 0; i < 16; ++i) {
                float v2 = on ? sM[i * 16 + j] : 0.f;
                if (i == j && !on) v2 = 1.f;
                a[i][j] = v2;
            }
        }
        float logdet = 0.f;
        #pragma unroll
        for (int k = 0; k < 16; ++k) {
            float piv = a[k][k];
            logdet += __logf(fabsf(piv));
            float inv = 1.0f / piv;
            #pragma unroll
            for (int i2 = k + 1; i2 < 16; ++i2) {
                float f = a[i2][k] * inv;
                #pragma unroll
                for (int j2 = k + 1; j2 < 16; ++j2)
                    a[i2][j2] = fmaf(-f, a[k][j2], a[i2][j2]);
            }
        }
        out[b] += logdet;
    }
}

extern "C" void kernel_launch(void* const* d_in, const int* in_sizes, int n_in,
                              void* d_out, int out_size, void* d_ws, size_t ws_size,
                              hipStream_t stream) {
    const int4*  x = (const int4*)d_in[0];
    const float* W = (const float*)d_in[1];
    const float* A = (const float*)d_in[2];
    const float* B = (const float*)d_in[3];
    const float* C = (const float*)d_in[4];
    float* ws  = (float*)d_ws;
    float* out = (float*)d_out;

    prep_kernel<<<1, 64, 0, stream>>>(W, A, B, C, ws);
    main_kernel<<<BATCH / 64, 1024, 0, stream>>>(x, ws, out);
    cleanup_kernel<<<8, 64, 0, stream>>>(ws, out);
}